// Round 6
// baseline (152.265 us; speedup 1.0000x reference)
//
#include <hip/hip_runtime.h>

#define NGRAPHS 256
#define DIM     256   // K (input dim)
#define HID     128   // N (hidden dim)
#define TILE    128   // rows per block

typedef __attribute__((ext_vector_type(8))) short bf16x8;
typedef __attribute__((ext_vector_type(4))) float f32x4;

__device__ __forceinline__ ushort f2bf_rne(float f) {
    unsigned u = __float_as_uint(f);
    unsigned r = u + 0x7fffu + ((u >> 16) & 1u);
    return (ushort)(r >> 16);
}
__device__ __forceinline__ float bf2f(ushort h) {
    return __uint_as_float(((unsigned)h) << 16);
}
__device__ __forceinline__ float tanh_fast(float x) {
    float e = __expf(2.0f * x);
    return 1.0f - 2.0f * __builtin_amdgcn_rcpf(1.0f + e);
}

// fire-and-forget global->LDS DMA, 16B per lane; lds ptr must be wave-uniform
__device__ __forceinline__ void glds16(const void* g, void* l) {
    __builtin_amdgcn_global_load_lds(
        (const __attribute__((address_space(1))) unsigned int*)g,
        (__attribute__((address_space(3))) unsigned int*)l, 16, 0, 0);
}

// split fp32 -> bf16 hi/lo in registers (hi = truncate, lo = truncate(f-hi))
__device__ __forceinline__ void cvt8(float4 v0, float4 v1, bf16x8& h, bf16x8& l) {
    float f[8] = {v0.x, v0.y, v0.z, v0.w, v1.x, v1.y, v1.z, v1.w};
    unsigned hu[8], lu[8];
#pragma unroll
    for (int i = 0; i < 8; ++i) {
        unsigned u = __float_as_uint(f[i]);
        unsigned hb = u & 0xffff0000u;
        hu[i] = u;
        lu[i] = __float_as_uint(f[i] - __uint_as_float(hb));
    }
    union { unsigned w[4]; bf16x8 v; } H, L;
#pragma unroll
    for (int j = 0; j < 4; ++j) {
        H.w[j] = (hu[2 * j] >> 16) | (hu[2 * j + 1] & 0xffff0000u);
        L.w[j] = (lu[2 * j] >> 16) | (lu[2 * j + 1] & 0xffff0000u);
    }
    h = H.v; l = L.v;
}

// ---------------------------------------------------------------------------
// Prep: w1 [256(k)][128(n)] fp32 -> fragment-major bf16 hi/lo:
//   w1f[(ks*8+nf)*1024 + plane*512 + lane*8 + j],
//   lane = lhi*16+llo, element = w1[ks*32+lhi*8+j][nf*16+llo]
// ---------------------------------------------------------------------------
__global__ void k_prep(const float* __restrict__ w1, ushort* __restrict__ w1f)
{
    int idx = blockIdx.x * 256 + threadIdx.x;   // 0..32767, k-major
    int k  = idx >> 7, nn = idx & 127;
    int ks = k >> 5, lhi = (k >> 3) & 3, j = k & 7;
    int nf = nn >> 4, llo = nn & 15;
    int lane = lhi * 16 + llo;
    float v = w1[idx];
    ushort hb = f2bf_rne(v);
    ushort lb = f2bf_rne(v - bf2f(hb));
    int base = (ks * 8 + nf) * 1024 + lane * 8 + j;
    w1f[base]       = hb;
    w1f[base + 512] = lb;
}

// ---------------------------------------------------------------------------
// Main: A-fragments global->reg (2-deep rotated), B via double-buffered
// global_load_lds; one barrier per k-step. Then tanh -> @w2 -> exp ->
// per-graph weighted partials + block exp-sum. Deterministic.
// ---------------------------------------------------------------------------
__global__ __launch_bounds__(256, 4) void k_scores(
    const float* __restrict__ x, const int* __restrict__ batch,
    const ushort* __restrict__ w1f,
    const float* __restrict__ b1, const float* __restrict__ w2,
    const float* __restrict__ b2,
    float* __restrict__ wsp, float* __restrict__ wse, int* __restrict__ wsid,
    int n)
{
    // 32 KB B ping-pong; dead after the GEMM loop -> first 8 KB re-used as
    // the phase-B cross-wave reduction buffer.
    __shared__ __align__(16) ushort bs[2][8 * 1024];
    __shared__ float evals[TILE];
    __shared__ int   gid[TILE];
    __shared__ float ep[4];
    float (*sred)[2][DIM] = (float(*)[2][DIM])&bs[0][0];   // alias, 8 KB

    const int t    = threadIdx.x;
    const int b    = blockIdx.x;
    const int r0   = b * TILE;
    const int wid  = t >> 6;
    const int lane = t & 63;
    const int lhi  = lane >> 4;
    const int llo  = lane & 15;

    if (t < TILE) {
        int r = r0 + t;
        gid[t] = batch[r < n ? r : (n - 1)];
    }

    // B staging addresses (hoisted; LDS dest wave-uniform)
    size_t boff[4];
    int    bl[4];
#pragma unroll
    for (int i = 0; i < 4; ++i) {
        boff[i] = (size_t)(i * 256 + t) * 8;
        bl[i]   = (i * 256 + wid * 64) * 8;
    }

#define STAGE_B(sel, KS) do {                                         \
    _Pragma("unroll")                                                 \
    for (int i = 0; i < 4; ++i)                                       \
        glds16(w1f + (size_t)(KS) * 8192 + boff[i], &bs[sel][bl[i]]); \
} while (0)

    // this lane's two A-fragment rows (mf=0,1)
    int row0 = r0 + wid * 32 + llo;
    int row1 = row0 + 16;
    if (row0 >= n) row0 = n - 1;
    if (row1 >= n) row1 = n - 1;
    const float* xr0 = x + (size_t)row0 * DIM + lhi * 8;
    const float* xr1 = x + (size_t)row1 * DIM + lhi * 8;

    f32x4 acc[2][8];
#pragma unroll
    for (int i = 0; i < 2; ++i)
#pragma unroll
        for (int j = 0; j < 8; ++j) acc[i][j] = (f32x4){0.f, 0.f, 0.f, 0.f};

    // 2-deep A-register pipeline (all indices static under full unroll)
    float4 pA[2], pB[2], pC[2], pD[2];
    pA[0] = *(const float4*)(xr0);
    pB[0] = *(const float4*)(xr0 + 4);
    pC[0] = *(const float4*)(xr1);
    pD[0] = *(const float4*)(xr1 + 4);
    STAGE_B(0, 0);
    __syncthreads();   // drains A(0) + B(0)

#pragma unroll
    for (int ks = 0; ks < 8; ++ks) {
        const int cur = ks & 1;
        if (ks < 7) {
            pA[cur ^ 1] = *(const float4*)(xr0 + (ks + 1) * 32);
            pB[cur ^ 1] = *(const float4*)(xr0 + (ks + 1) * 32 + 4);
            pC[cur ^ 1] = *(const float4*)(xr1 + (ks + 1) * 32);
            pD[cur ^ 1] = *(const float4*)(xr1 + (ks + 1) * 32 + 4);
            STAGE_B(cur ^ 1, ks + 1);
        }

        bf16x8 ah0, al0, ah1, al1;
        cvt8(pA[cur], pB[cur], ah0, al0);
        cvt8(pC[cur], pD[cur], ah1, al1);

#pragma unroll
        for (int nf = 0; nf < 8; ++nf) {
            bf16x8 bh = *(const bf16x8*)&bs[cur][(nf * 2 + 0) * 512 + lane * 8];
            bf16x8 bl16 = *(const bf16x8*)&bs[cur][(nf * 2 + 1) * 512 + lane * 8];
            acc[0][nf] = __builtin_amdgcn_mfma_f32_16x16x32_bf16(ah0, bh,   acc[0][nf], 0, 0, 0);
            acc[1][nf] = __builtin_amdgcn_mfma_f32_16x16x32_bf16(ah1, bh,   acc[1][nf], 0, 0, 0);
            acc[0][nf] = __builtin_amdgcn_mfma_f32_16x16x32_bf16(ah0, bl16, acc[0][nf], 0, 0, 0);
            acc[1][nf] = __builtin_amdgcn_mfma_f32_16x16x32_bf16(ah1, bl16, acc[1][nf], 0, 0, 0);
            acc[0][nf] = __builtin_amdgcn_mfma_f32_16x16x32_bf16(al0, bh,   acc[0][nf], 0, 0, 0);
            acc[1][nf] = __builtin_amdgcn_mfma_f32_16x16x32_bf16(al1, bh,   acc[1][nf], 0, 0, 0);
        }
        __syncthreads();   // drains next-step A+B (full compute phase to land)
    }
#undef STAGE_B

    // ---- epilogue: tanh + dot(w2); C layout: col=llo+16nf, row=lhi*4+rg ----
    float b2v = b2[0];
    float b1v[8], w2v[8];
#pragma unroll
    for (int nf = 0; nf < 8; ++nf) {
        b1v[nf] = b1[nf * 16 + llo];
        w2v[nf] = w2[nf * 16 + llo];
    }
    float sc[8];
#pragma unroll
    for (int mf = 0; mf < 2; ++mf)
#pragma unroll
        for (int rg = 0; rg < 4; ++rg) {
            float p = 0.f;
#pragma unroll
            for (int nf = 0; nf < 8; ++nf)
                p += tanh_fast(acc[mf][nf][rg] + b1v[nf]) * w2v[nf];
            sc[mf * 4 + rg] = p;
        }
#pragma unroll
    for (int off = 1; off < 16; off <<= 1)
#pragma unroll
        for (int q = 0; q < 8; ++q) sc[q] += __shfl_xor(sc[q], off, 64);

    if (llo == 0) {
#pragma unroll
        for (int mf = 0; mf < 2; ++mf)
#pragma unroll
            for (int rg = 0; rg < 4; ++rg) {
                int row = wid * 32 + mf * 16 + lhi * 4 + rg;
                float s = sc[mf * 4 + rg] + b2v;
                evals[row] = (r0 + row < n) ? __expf(s) : 0.f;
            }
    }
    __syncthreads();   // evals visible; bs arena now dead -> sred alias ok

    // ---- phase B: weighted per-graph column partials, 8-deep load batches ----
    {
        const int g0 = gid[0];
        float4 a0 = {0.f, 0.f, 0.f, 0.f}, a1 = {0.f, 0.f, 0.f, 0.f};
        for (int bt = 0; bt < 4; ++bt) {
            float4 xv[8];
#pragma unroll
            for (int j = 0; j < 8; ++j) {
                int rsrc = r0 + wid * 32 + bt * 8 + j;
                if (rsrc >= n) rsrc = n - 1;          // e==0 there anyway
                xv[j] = *(const float4*)(x + (size_t)rsrc * DIM + lane * 4);
            }
#pragma unroll
            for (int j = 0; j < 8; ++j) {
                int row = wid * 32 + bt * 8 + j;
                float e = evals[row];
                if (gid[row] != g0) {
                    a1.x = fmaf(e, xv[j].x, a1.x); a1.y = fmaf(e, xv[j].y, a1.y);
                    a1.z = fmaf(e, xv[j].z, a1.z); a1.w = fmaf(e, xv[j].w, a1.w);
                } else {
                    a0.x = fmaf(e, xv[j].x, a0.x); a0.y = fmaf(e, xv[j].y, a0.y);
                    a0.z = fmaf(e, xv[j].z, a0.z); a0.w = fmaf(e, xv[j].w, a0.w);
                }
            }
        }
        *(float4*)&sred[wid][0][lane * 4] = a0;
        *(float4*)&sred[wid][1][lane * 4] = a1;
    }
    __syncthreads();
    {
        float s0 = sred[0][0][t] + sred[1][0][t] + sred[2][0][t] + sred[3][0][t];
        float s1 = sred[0][1][t] + sred[1][1][t] + sred[2][1][t] + sred[3][1][t];
        wsp[(size_t)b * 512 + t]       = s0;
        wsp[(size_t)b * 512 + 256 + t] = s1;
        if (t == 0) wsid[b] = gid[0];
    }

    // ---- block exp-sum (deterministic) ----
    float rsum = (t < TILE) ? evals[t] : 0.f;
#pragma unroll
    for (int off = 32; off; off >>= 1) rsum += __shfl_down(rsum, off, 64);
    if ((t & 63) == 0) ep[t >> 6] = rsum;
    __syncthreads();
    if (t == 0) wse[b] = ep[0] + ep[1];
}

// ---------------------------------------------------------------------------
// Combine: one block per graph
// ---------------------------------------------------------------------------
__global__ __launch_bounds__(256) void k_combine(
    const int* __restrict__ batch, const float* __restrict__ wsp,
    const float* __restrict__ wse, const int* __restrict__ wsid,
    float* __restrict__ out, int n, int nblk)
{
    __shared__ float sred[256];
    __shared__ int bounds[2];
    const int g = blockIdx.x;
    const int d = threadIdx.x;

    float p = 0.f;
    for (int i = d; i < nblk; i += 256) p += wse[i];
    sred[d] = p;
    __syncthreads();
    for (int s = 128; s; s >>= 1) {
        if (d < s) sred[d] += sred[d + s];
        __syncthreads();
    }
    const float S = sred[0];

    if (d < 2) {
        int v = g + d;
        int lo = 0, hi = n;
        while (lo < hi) { int mid = (lo + hi) >> 1; if (batch[mid] < v) lo = mid + 1; else hi = mid; }
        bounds[d] = lo;
    }
    __syncthreads();

    const int st = bounds[0], en = bounds[1];
    float acc = 0.f;
    if (st < en) {
        for (int bb = st >> 7; bb <= (en - 1) >> 7; ++bb) {
            int slot = (wsid[bb] == g) ? 0 : 1;
            acc += wsp[(size_t)bb * 512 + slot * 256 + d];
        }
    }
    out[g * 256 + d] = acc / S;
}

// ---------------------------------------------------------------------------
extern "C" void kernel_launch(void* const* d_in, const int* in_sizes, int n_in,
                              void* d_out, int out_size, void* d_ws, size_t ws_size,
                              hipStream_t stream)
{
    const float* x     = (const float*)d_in[0];
    const int*   batch = (const int*)d_in[1];
    const float* w1    = (const float*)d_in[2];
    const float* b1    = (const float*)d_in[3];
    const float* w2    = (const float*)d_in[4];
    const float* b2    = (const float*)d_in[5];
    float* out = (float*)d_out;

    const int n    = in_sizes[1];                 // 200000
    const int nblk = (n + TILE - 1) / TILE;       // 1563

    // ws layout: w1f fragment-major hi/lo (128KB) | wsp | wse | wsid
    ushort* w1f = (ushort*)d_ws;
    float*  wsp = (float*)((char*)d_ws + (size_t)DIM * HID * 2 * sizeof(ushort));
    float*  wse = wsp + (size_t)nblk * 512;
    int*    wsid = (int*)(wse + nblk);

    k_prep<<<dim3(DIM * HID / 256), dim3(256), 0, stream>>>(w1, w1f);
    k_scores<<<dim3(nblk), dim3(256), 0, stream>>>(x, batch, w1f,
                                                   b1, w2, b2, wsp, wse, wsid, n);
    k_combine<<<dim3(NGRAPHS), dim3(256), 0, stream>>>(batch, wsp, wse, wsid,
                                                       out, n, nblk);
}

// Round 7
// 95.969 us; speedup vs baseline: 1.5866x; 1.5866x over previous
//
#include <hip/hip_runtime.h>

#define NGRAPHS 256
#define DIM     256   // K (input dim)
#define HID     128   // N (hidden dim)
#define TILE    128   // rows per block

typedef __attribute__((ext_vector_type(8))) short bf16x8;
typedef __attribute__((ext_vector_type(4))) float f32x4;

__device__ __forceinline__ ushort f2bf_rne(float f) {
    unsigned u = __float_as_uint(f);
    unsigned r = u + 0x7fffu + ((u >> 16) & 1u);
    return (ushort)(r >> 16);
}
__device__ __forceinline__ float bf2f(ushort h) {
    return __uint_as_float(((unsigned)h) << 16);
}
__device__ __forceinline__ float tanh_fast(float x) {
    float e = __expf(2.0f * x);
    return 1.0f - 2.0f * __builtin_amdgcn_rcpf(1.0f + e);
}

// fire-and-forget global->LDS DMA, 16B per lane; lds ptr must be wave-uniform
__device__ __forceinline__ void glds16(const void* g, void* l) {
    __builtin_amdgcn_global_load_lds(
        (const __attribute__((address_space(1))) unsigned int*)g,
        (__attribute__((address_space(3))) unsigned int*)l, 16, 0, 0);
}

// split fp32 -> bf16 hi/lo in registers (hi = truncate, lo = truncate(f-hi))
__device__ __forceinline__ void cvt8(float4 v0, float4 v1, bf16x8& h, bf16x8& l) {
    float f[8] = {v0.x, v0.y, v0.z, v0.w, v1.x, v1.y, v1.z, v1.w};
    unsigned hu[8], lu[8];
#pragma unroll
    for (int i = 0; i < 8; ++i) {
        unsigned u = __float_as_uint(f[i]);
        unsigned hb = u & 0xffff0000u;
        hu[i] = u;
        lu[i] = __float_as_uint(f[i] - __uint_as_float(hb));
    }
    union { unsigned w[4]; bf16x8 v; } H, L;
#pragma unroll
    for (int j = 0; j < 4; ++j) {
        H.w[j] = (hu[2 * j] >> 16) | (hu[2 * j + 1] & 0xffff0000u);
        L.w[j] = (lu[2 * j] >> 16) | (lu[2 * j + 1] & 0xffff0000u);
    }
    h = H.v; l = L.v;
}

// ---------------------------------------------------------------------------
// Prep: w1 [256(k)][128(n)] fp32 -> fragment-major bf16 hi/lo:
//   w1f[(ks*8+nf)*1024 + plane*512 + lane*8 + j],
//   lane = lhi*16+llo, element = w1[ks*32+lhi*8+j][nf*16+llo]
// ---------------------------------------------------------------------------
__global__ void k_prep(const float* __restrict__ w1, ushort* __restrict__ w1f)
{
    int idx = blockIdx.x * 256 + threadIdx.x;   // 0..32767, k-major
    int k  = idx >> 7, nn = idx & 127;
    int ks = k >> 5, lhi = (k >> 3) & 3, j = k & 7;
    int nf = nn >> 4, llo = nn & 15;
    int lane = lhi * 16 + llo;
    float v = w1[idx];
    ushort hb = f2bf_rne(v);
    ushort lb = f2bf_rne(v - bf2f(hb));
    int base = (ks * 8 + nf) * 1024 + lane * 8 + j;
    w1f[base]       = hb;
    w1f[base + 512] = lb;
}

// ---------------------------------------------------------------------------
// Main: double-buffered global_load_lds pipeline with COUNTED vmcnt + raw
// barriers (T3+T4): prefetch stays in flight across barriers; vmcnt never
// drains to 0 in the main loop. Then tanh -> @w2 -> exp -> per-graph
// weighted partials + block exp-sum. Deterministic.
// ---------------------------------------------------------------------------
__global__ __launch_bounds__(256, 2) void k_scores(
    const float* __restrict__ x, const int* __restrict__ batch,
    const ushort* __restrict__ w1f,
    const float* __restrict__ b1, const float* __restrict__ w2,
    const float* __restrict__ b2,
    float* __restrict__ wsp, float* __restrict__ wse, int* __restrict__ wsid,
    int n)
{
    // 64 KB ping-pong staging arena; dead after the GEMM loop -> first 8 KB
    // re-used as the phase-B cross-wave reduction buffer.
    __shared__ __align__(16) unsigned char smem[65536];
    float  (*xs)[TILE * 32] = (float(*)[TILE * 32])smem;             // 2 x 16 KB
    ushort (*bs)[8 * 1024]  = (ushort(*)[8 * 1024])(smem + 32768);   // 2 x 16 KB
    float  (*sred)[2][DIM]  = (float(*)[2][DIM])smem;                // alias, 8 KB
    __shared__ float evals[TILE];
    __shared__ int   gid[TILE];
    __shared__ float ep[4];

    const int t    = threadIdx.x;
    const int b    = blockIdx.x;
    const int r0   = b * TILE;
    const int wid  = t >> 6;
    const int lane = t & 63;
    const int lhi  = lane >> 4;
    const int llo  = lane & 15;

    if (t < TILE) {
        int r = r0 + t;
        gid[t] = batch[r < n ? r : (n - 1)];
    }

    // hoisted staging addresses: 16B-chunk XOR swizzle on the SOURCE side,
    // linear LDS dest (both-sides-or-neither rule).
    size_t xoff[4], boff[4];
    int    xl[4], bl[4];
#pragma unroll
    for (int i = 0; i < 4; ++i) {
        int p = i * 256 + t;            // 16B-chunk index 0..1023
        int r = p >> 3, s = p & 7;
        int q = s ^ (r & 7);
        int rsrc = r0 + r; if (rsrc >= n) rsrc = n - 1;
        xoff[i] = (size_t)rsrc * DIM + q * 4;
        boff[i] = (size_t)p * 8;
        xl[i]   = (i * 256 + wid * 64) * 4;   // float index (wave-uniform)
        bl[i]   = (i * 256 + wid * 64) * 8;   // ushort index (wave-uniform)
    }

#define STAGE(sel, KS) do {                                          \
    _Pragma("unroll")                                                \
    for (int i = 0; i < 4; ++i) {                                    \
        glds16(x + xoff[i] + (KS) * 32, &xs[sel][xl[i]]);            \
        glds16(w1f + (size_t)(KS) * 8192 + boff[i], &bs[sel][bl[i]]);\
    }                                                                \
} while (0)

    f32x4 acc[2][8];
#pragma unroll
    for (int i = 0; i < 2; ++i)
#pragma unroll
        for (int j = 0; j < 8; ++j) acc[i][j] = (f32x4){0.f, 0.f, 0.f, 0.f};

    // A-fragment LDS chunk addresses (block-relative rows ra0, ra0+16)
    const int ra0 = wid * 32 + llo;
    const int ra1 = ra0 + 16;               // (ra1 & 7) == (ra0 & 7)
    const int rb7 = ra0 & 7;
    const int c00 = (ra0 * 8 + ((2 * lhi)     ^ rb7)) * 4;
    const int c01 = (ra0 * 8 + ((2 * lhi + 1) ^ rb7)) * 4;
    const int c10 = (ra1 * 8 + ((2 * lhi)     ^ rb7)) * 4;
    const int c11 = (ra1 * 8 + ((2 * lhi + 1) ^ rb7)) * 4;

    // ---- pipelined K-loop: counted vmcnt, prefetch never drained ----
    STAGE(0, 0);   // 8 loads/thread in flight
#pragma unroll
    for (int ks = 0; ks < 8; ++ks) {
        const int cur = ks & 1;
        if (ks < 7) {
            STAGE(cur ^ 1, ks + 1);   // +8 loads; outstanding <= 16
            // wait until only the prefetch's 8 remain -> cur fully staged
            asm volatile("s_waitcnt vmcnt(8)" ::: "memory");
        } else {
            asm volatile("s_waitcnt vmcnt(0)" ::: "memory");
        }
        __builtin_amdgcn_sched_barrier(0);
        __builtin_amdgcn_s_barrier();     // all waves' cur staged
        __builtin_amdgcn_sched_barrier(0);

        float4 a0 = *(const float4*)&xs[cur][c00];
        float4 a1 = *(const float4*)&xs[cur][c01];
        float4 c0 = *(const float4*)&xs[cur][c10];
        float4 c1 = *(const float4*)&xs[cur][c11];
        bf16x8 ah0, al0, ah1, al1;
        cvt8(a0, a1, ah0, al0);
        cvt8(c0, c1, ah1, al1);

#pragma unroll
        for (int nf = 0; nf < 8; ++nf) {
            bf16x8 bh = *(const bf16x8*)&bs[cur][(nf * 2 + 0) * 512 + lane * 8];
            bf16x8 bl16 = *(const bf16x8*)&bs[cur][(nf * 2 + 1) * 512 + lane * 8];
            acc[0][nf] = __builtin_amdgcn_mfma_f32_16x16x32_bf16(ah0, bh,   acc[0][nf], 0, 0, 0);
            acc[1][nf] = __builtin_amdgcn_mfma_f32_16x16x32_bf16(ah1, bh,   acc[1][nf], 0, 0, 0);
            acc[0][nf] = __builtin_amdgcn_mfma_f32_16x16x32_bf16(ah0, bl16, acc[0][nf], 0, 0, 0);
            acc[1][nf] = __builtin_amdgcn_mfma_f32_16x16x32_bf16(ah1, bl16, acc[1][nf], 0, 0, 0);
            acc[0][nf] = __builtin_amdgcn_mfma_f32_16x16x32_bf16(al0, bh,   acc[0][nf], 0, 0, 0);
            acc[1][nf] = __builtin_amdgcn_mfma_f32_16x16x32_bf16(al1, bh,   acc[1][nf], 0, 0, 0);
        }
        __builtin_amdgcn_sched_barrier(0);
        __builtin_amdgcn_s_barrier();     // all waves done READING cur
        __builtin_amdgcn_sched_barrier(0);
    }
#undef STAGE

    // ---- epilogue: tanh + dot(w2); C layout: col=llo+16nf, row=lhi*4+rg ----
    float b2v = b2[0];
    float b1v[8], w2v[8];
#pragma unroll
    for (int nf = 0; nf < 8; ++nf) {
        b1v[nf] = b1[nf * 16 + llo];
        w2v[nf] = w2[nf * 16 + llo];
    }
    float sc[8];
#pragma unroll
    for (int mf = 0; mf < 2; ++mf)
#pragma unroll
        for (int rg = 0; rg < 4; ++rg) {
            float p = 0.f;
#pragma unroll
            for (int nf = 0; nf < 8; ++nf)
                p += tanh_fast(acc[mf][nf][rg] + b1v[nf]) * w2v[nf];
            sc[mf * 4 + rg] = p;
        }
#pragma unroll
    for (int off = 1; off < 16; off <<= 1)
#pragma unroll
        for (int q = 0; q < 8; ++q) sc[q] += __shfl_xor(sc[q], off, 64);

    if (llo == 0) {
#pragma unroll
        for (int mf = 0; mf < 2; ++mf)
#pragma unroll
            for (int rg = 0; rg < 4; ++rg) {
                int row = wid * 32 + mf * 16 + lhi * 4 + rg;
                float s = sc[mf * 4 + rg] + b2v;
                evals[row] = (r0 + row < n) ? __expf(s) : 0.f;
            }
    }
    __syncthreads();   // evals visible; staging arena dead -> sred alias ok

    // ---- phase B: weighted per-graph column partials, 8-deep load batches ----
    {
        const int g0 = gid[0];
        float4 a0 = {0.f, 0.f, 0.f, 0.f}, a1 = {0.f, 0.f, 0.f, 0.f};
        for (int bt = 0; bt < 4; ++bt) {
            float4 xv[8];
#pragma unroll
            for (int j = 0; j < 8; ++j) {
                int rsrc = r0 + wid * 32 + bt * 8 + j;
                if (rsrc >= n) rsrc = n - 1;          // e==0 there anyway
                xv[j] = *(const float4*)(x + (size_t)rsrc * DIM + lane * 4);
            }
#pragma unroll
            for (int j = 0; j < 8; ++j) {
                int row = wid * 32 + bt * 8 + j;
                float e = evals[row];
                if (gid[row] != g0) {
                    a1.x = fmaf(e, xv[j].x, a1.x); a1.y = fmaf(e, xv[j].y, a1.y);
                    a1.z = fmaf(e, xv[j].z, a1.z); a1.w = fmaf(e, xv[j].w, a1.w);
                } else {
                    a0.x = fmaf(e, xv[j].x, a0.x); a0.y = fmaf(e, xv[j].y, a0.y);
                    a0.z = fmaf(e, xv[j].z, a0.z); a0.w = fmaf(e, xv[j].w, a0.w);
                }
            }
        }
        *(float4*)&sred[wid][0][lane * 4] = a0;
        *(float4*)&sred[wid][1][lane * 4] = a1;
    }
    __syncthreads();
    {
        float s0 = sred[0][0][t] + sred[1][0][t] + sred[2][0][t] + sred[3][0][t];
        float s1 = sred[0][1][t] + sred[1][1][t] + sred[2][1][t] + sred[3][1][t];
        wsp[(size_t)b * 512 + t]       = s0;
        wsp[(size_t)b * 512 + 256 + t] = s1;
        if (t == 0) wsid[b] = gid[0];
    }

    // ---- block exp-sum (deterministic) ----
    float rsum = (t < TILE) ? evals[t] : 0.f;
#pragma unroll
    for (int off = 32; off; off >>= 1) rsum += __shfl_down(rsum, off, 64);
    if ((t & 63) == 0) ep[t >> 6] = rsum;
    __syncthreads();
    if (t == 0) wse[b] = ep[0] + ep[1];
}

// ---------------------------------------------------------------------------
// Combine: one block per graph
// ---------------------------------------------------------------------------
__global__ __launch_bounds__(256) void k_combine(
    const int* __restrict__ batch, const float* __restrict__ wsp,
    const float* __restrict__ wse, const int* __restrict__ wsid,
    float* __restrict__ out, int n, int nblk)
{
    __shared__ float sred[256];
    __shared__ int bounds[2];
    const int g = blockIdx.x;
    const int d = threadIdx.x;

    float p = 0.f;
    for (int i = d; i < nblk; i += 256) p += wse[i];
    sred[d] = p;
    __syncthreads();
    for (int s = 128; s; s >>= 1) {
        if (d < s) sred[d] += sred[d + s];
        __syncthreads();
    }
    const float S = sred[0];

    if (d < 2) {
        int v = g + d;
        int lo = 0, hi = n;
        while (lo < hi) { int mid = (lo + hi) >> 1; if (batch[mid] < v) lo = mid + 1; else hi = mid; }
        bounds[d] = lo;
    }
    __syncthreads();

    const int st = bounds[0], en = bounds[1];
    float acc = 0.f;
    if (st < en) {
        for (int bb = st >> 7; bb <= (en - 1) >> 7; ++bb) {
            int slot = (wsid[bb] == g) ? 0 : 1;
            acc += wsp[(size_t)bb * 512 + slot * 256 + d];
        }
    }
    out[g * 256 + d] = acc / S;
}

// ---------------------------------------------------------------------------
extern "C" void kernel_launch(void* const* d_in, const int* in_sizes, int n_in,
                              void* d_out, int out_size, void* d_ws, size_t ws_size,
                              hipStream_t stream)
{
    const float* x     = (const float*)d_in[0];
    const int*   batch = (const int*)d_in[1];
    const float* w1    = (const float*)d_in[2];
    const float* b1    = (const float*)d_in[3];
    const float* w2    = (const float*)d_in[4];
    const float* b2    = (const float*)d_in[5];
    float* out = (float*)d_out;

    const int n    = in_sizes[1];                 // 200000
    const int nblk = (n + TILE - 1) / TILE;       // 1563

    // ws layout: w1f fragment-major hi/lo (128KB) | wsp | wse | wsid
    ushort* w1f = (ushort*)d_ws;
    float*  wsp = (float*)((char*)d_ws + (size_t)DIM * HID * 2 * sizeof(ushort));
    float*  wse = wsp + (size_t)nblk * 512;
    int*    wsid = (int*)(wse + nblk);

    k_prep<<<dim3(DIM * HID / 256), dim3(256), 0, stream>>>(w1, w1f);
    k_scores<<<dim3(nblk), dim3(256), 0, stream>>>(x, batch, w1f,
                                                   b1, w2, b2, wsp, wse, wsid, n);
    k_combine<<<dim3(NGRAPHS), dim3(256), 0, stream>>>(batch, wsp, wse, wsid,
                                                       out, n, nblk);
}